// Round 8
// baseline (195.378 us; speedup 1.0000x reference)
//
#include <hip/hip_runtime.h>
#include <hip/hip_bf16.h>

// VariableSelectionNetwork fused kernel, round 8.
//
// Live computation (sel fc1/fc2 and the nvh,vho einsum are dead in the ref):
//   weights = softmax(LN(GLU(x @ sel_gate_w + b) + x))            [N,32]
//   y[n,v,o] = sigmoid(x*gw+gb)*(x*gw'+gb') + (x*sw+sb)           [N,32,256]
//   out[n,o] = sum_v weights[n,v] * LN_o(y)[.,v,.]                [N,256]
//
// R4-R7 all staged weights in LDS and re-read them per wave per v: the
// structure serializes on ds_read + barrier-per-chunk, stuck ~30us.
// R8 inverts: wave w holds variables 2w,2w+1's weights in 64 VGPRs
// permanently (strided: lane l owns cols l,l+64,l+128,l+192), loops over
// the block's 16 rows with NO barriers / NO weight re-reads. Per-row
// cross-variable sum via ds_add_f32 (atomicAdd on LDS; stride-4B =
// conflict-free; wave-staggered row order -> no same-address contention).
// Sigmoid in exp2 form with -log2(e) folded into gate weights.

#define VDIM 32
#define ODIM 256
#define RPB  16          // rows per block
#define TPB  1024        // 16 waves, 4/SIMD

// DPP-add: x += dpp_moved(x), 0-filled for invalid source lanes. Pure VALU.
template <int CTRL>
__device__ __forceinline__ float dpp_add(float x) {
    int s = __builtin_amdgcn_update_dpp(0, __builtin_bit_cast(int, x),
                                        CTRL, 0xF, 0xF, true);
    return x + __builtin_bit_cast(float, s);
}

// Wave64 sum -> uniform value via readlane 63. No DS-pipe ops.
__device__ __forceinline__ float wave_sum(float x) {
    x = dpp_add<0x111>(x);   // row_shr:1
    x = dpp_add<0x112>(x);   // row_shr:2
    x = dpp_add<0x114>(x);   // row_shr:4
    x = dpp_add<0x118>(x);   // row_shr:8
    x = dpp_add<0x142>(x);   // row_bcast:15
    x = dpp_add<0x143>(x);   // row_bcast:31 -> lane 63 holds total
    return __builtin_bit_cast(float,
        __builtin_amdgcn_readlane(__builtin_bit_cast(int, x), 63));
}

__device__ __forceinline__ float fast_sigmoid(float g) {
    return __builtin_amdgcn_rcpf(1.0f + __expf(-g));
}

__global__ void __launch_bounds__(TPB, 4) vsn_fused(
    const float* __restrict__ x,     // [N,32]
    const float* __restrict__ sgw,   // [32,64]
    const float* __restrict__ sgb,   // [64]
    const float* __restrict__ slg,   // [32]
    const float* __restrict__ slb,   // [32]
    const float* __restrict__ vgw,   // [32,512]
    const float* __restrict__ vgb,   // [32,512]
    const float* __restrict__ vsw,   // [32,256]
    const float* __restrict__ vsb,   // [32,256]
    const float* __restrict__ vlg,   // [32,256]
    const float* __restrict__ vlb,   // [32,256]
    float* __restrict__ out)         // [N,256]
{
    __shared__ float acc_s[RPB * ODIM];      // 16KB per-row output accumulators
    __shared__ float x_s[RPB][VDIM];         // 2KB
    __shared__ float g_s[RPB][2 * VDIM];     // 4KB
    __shared__ float w_s[RPB][VDIM];         // 2KB

    const int tid  = threadIdx.x;
    const int row0 = blockIdx.x * RPB;
    const int wave = tid >> 6;               // 0..15
    const int lane = tid & 63;
    const int v0   = wave * 2;               // this wave's two variables

    // ---- load this wave's weights into registers (issued first; the HBM
    // latency hides under acc-zeroing + Phase A). Strided layout: lane l
    // owns cols l, l+64, l+128, l+192. All array indices compile-time.
    float ga[2][4], gb[2][4], va[2][4], vb[2][4];
    float sw[2][4], sb[2][4], lg[2][4], lb[2][4];
    #pragma unroll
    for (int j = 0; j < 2; ++j) {
        const int v = v0 + j;
        #pragma unroll
        for (int k = 0; k < 4; ++k) {
            const int c = lane + 64 * k;
            ga[j][k] = vgw[v * 512 + c];
            va[j][k] = vgw[v * 512 + 256 + c];
            gb[j][k] = vgb[v * 512 + c];
            vb[j][k] = vgb[v * 512 + 256 + c];
            sw[j][k] = vsw[v * 256 + c];
            sb[j][k] = vsb[v * 256 + c];
            lg[j][k] = vlg[v * 256 + c];
            lb[j][k] = vlb[v * 256 + c];
        }
    }

    // ---- zero the output accumulators (re-poisoned to 0xAA by harness) ----
    *(float4*)(acc_s + (tid << 2)) = make_float4(0.f, 0.f, 0.f, 0.f);

    // ---- load x rows (16*32 = 512 floats) ----
    if (tid < RPB * VDIM)
        ((float*)x_s)[tid] = x[row0 * VDIM + tid];
    __syncthreads();

    // ---- Phase A1: g = x @ sel_gate_w + b (16 rows x 64 cols = 1024 tasks) ----
    {
        const int r = tid >> 6, j = tid & 63;
        float acc = sgb[j];
        #pragma unroll
        for (int v = 0; v < VDIM; ++v)
            acc = fmaf(x_s[r][v], sgw[v * 64 + j], acc);
        g_s[r][j] = acc;
    }
    __syncthreads();

    // ---- Phase A2: GLU -> +x -> LN(32) -> softmax(32) -> weights ----
    if (tid < RPB * VDIM) {
        const int r = tid >> 5, v = tid & 31;
        const float gate = g_s[r][v];
        const float val  = g_s[r][VDIM + v];
        const float y    = fast_sigmoid(gate) * val + x_s[r][v];
        float s1 = y, s2 = y * y;
        #pragma unroll
        for (int m = 1; m < 32; m <<= 1) {
            s1 += __shfl_xor(s1, m, 64);
            s2 += __shfl_xor(s2, m, 64);
        }
        const float mean = s1 * (1.0f / VDIM);
        const float var  = s2 * (1.0f / VDIM) - mean * mean;
        const float rs   = __builtin_amdgcn_rsqf(var + 1e-5f);
        const float sel  = slg[v] * ((y - mean) * rs) + slb[v];
        float mx = sel;
        #pragma unroll
        for (int m = 1; m < 32; m <<= 1)
            mx = fmaxf(mx, __shfl_xor(mx, m, 64));
        const float e = __expf(sel - mx);
        float se = e;
        #pragma unroll
        for (int m = 1; m < 32; m <<= 1)
            se += __shfl_xor(se, m, 64);
        w_s[r][v] = e * __builtin_amdgcn_rcpf(se);
    }
    __syncthreads();

    // ---- fold sigmoid into exp2 form: sig(g) = rcp(1 + 2^(-g*log2e)) ----
    constexpr float NL2E = -1.4426950408889634f;
    #pragma unroll
    for (int j = 0; j < 2; ++j)
        #pragma unroll
        for (int k = 0; k < 4; ++k) { ga[j][k] *= NL2E; gb[j][k] *= NL2E; }

    // ---- Phase B: loop rows, no barriers. Wave-staggered row order so no
    // two waves ds_add the same row concurrently. ----
    for (int i = 0; i < RPB; ++i) {
        const int r  = (wave + i) & (RPB - 1);
        const float xa = x_s[r][v0];         // LDS broadcast reads
        const float xb = x_s[r][v0 + 1];
        const float wa = w_s[r][v0];
        const float wb = w_s[r][v0 + 1];

        float yA[4], yB[4];
        #pragma unroll
        for (int k = 0; k < 4; ++k) {
            const float eA = __builtin_amdgcn_exp2f(fmaf(xa, ga[0][k], gb[0][k]));
            const float sA = __builtin_amdgcn_rcpf(1.0f + eA);
            yA[k] = fmaf(sA, fmaf(xa, va[0][k], vb[0][k]), fmaf(xa, sw[0][k], sb[0][k]));
            const float eB = __builtin_amdgcn_exp2f(fmaf(xb, ga[1][k], gb[1][k]));
            const float sB = __builtin_amdgcn_rcpf(1.0f + eB);
            yB[k] = fmaf(sB, fmaf(xb, va[1][k], vb[1][k]), fmaf(xb, sw[1][k], sb[1][k]));
        }

        const float s1a = wave_sum((yA[0] + yA[1]) + (yA[2] + yA[3]));
        const float s2a = wave_sum(fmaf(yA[0], yA[0], fmaf(yA[1], yA[1],
                                   fmaf(yA[2], yA[2], yA[3] * yA[3]))));
        const float s1b = wave_sum((yB[0] + yB[1]) + (yB[2] + yB[3]));
        const float s2b = wave_sum(fmaf(yB[0], yB[0], fmaf(yB[1], yB[1],
                                   fmaf(yB[2], yB[2], yB[3] * yB[3]))));

        const float mA  = s1a * (1.0f / ODIM);
        const float vA  = s2a * (1.0f / ODIM) - mA * mA;
        const float rsA = __builtin_amdgcn_rsqf(vA + 1e-5f);
        const float wrsA = wa * rsA;
        const float mB  = s1b * (1.0f / ODIM);
        const float vB  = s2b * (1.0f / ODIM) - mB * mB;
        const float rsB = __builtin_amdgcn_rsqf(vB + 1e-5f);
        const float wrsB = wb * rsB;

        #pragma unroll
        for (int k = 0; k < 4; ++k) {
            const float c = fmaf(lg[0][k], (yA[k] - mA) * wrsA, wa * lb[0][k])
                          + fmaf(lg[1][k], (yB[k] - mB) * wrsB, wb * lb[1][k]);
            atomicAdd(&acc_s[r * ODIM + lane + 64 * k], c);  // ds_add_f32
        }
    }
    __syncthreads();

    // ---- epilogue: wave w writes row w ----
    const float4 o4 = *(const float4*)(acc_s + wave * ODIM + (lane << 2));
    *(float4*)(out + (size_t)(row0 + wave) * ODIM + (lane << 2)) = o4;
}

extern "C" void kernel_launch(void* const* d_in, const int* in_sizes, int n_in,
                              void* d_out, int out_size, void* d_ws, size_t ws_size,
                              hipStream_t stream) {
    const float* x   = (const float*)d_in[0];
    const float* sgw = (const float*)d_in[5];
    const float* sgb = (const float*)d_in[6];
    const float* slg = (const float*)d_in[7];
    const float* slb = (const float*)d_in[8];
    const float* vgw = (const float*)d_in[13];
    const float* vgb = (const float*)d_in[14];
    const float* vsw = (const float*)d_in[15];
    const float* vsb = (const float*)d_in[16];
    const float* vlg = (const float*)d_in[17];
    const float* vlb = (const float*)d_in[18];
    float* out = (float*)d_out;

    const int N = in_sizes[0] / VDIM;      // 4096 rows
    const int grid = N / RPB;              // 256 blocks, 1 per CU

    vsn_fused<<<grid, TPB, 0, stream>>>(x, sgw, sgb, slg, slb,
                                        vgw, vgb, vsw, vsb, vlg, vlb, out);
}

// Round 9
// 194.760 us; speedup vs baseline: 1.0032x; 1.0032x over previous
//
#include <hip/hip_runtime.h>
#include <hip/hip_bf16.h>

// VariableSelectionNetwork fused kernel, round 9.
//
// Live computation (sel fc1/fc2 and the nvh,vho einsum are dead in the ref):
//   weights = softmax(LN(GLU(x @ sel_gate_w + b) + x))            [N,32]
//   y[n,v,o] = sigmoid(x*gw+gb)*(x*gw'+gb') + (x*sw+sb)           [N,32,256]
//   out[n,o] = sum_v weights[n,v] * LN_o(y)[.,v,.]                [N,256]
//
// R8 structure (wave owns 2 vars, weights in 64 VGPRs, barrier-free row loop,
// ds_add_f32 output combine) failed at CODEGEN: VGPR_Count=48 proved the
// compiler sank the weight loads into the row loop (1024 VMEM instr/thread,
// VALUBusy 17%, 106us). R9 pins all 64 weight values with opaque
// asm ("+v") after the exp2-fold: rematerialization becomes impossible,
// forcing true register residency across the loop.

#define VDIM 32
#define ODIM 256
#define RPB  16          // rows per block
#define TPB  1024        // 16 waves, 4/SIMD

// DPP-add: x += dpp_moved(x), 0-filled for invalid source lanes. Pure VALU.
template <int CTRL>
__device__ __forceinline__ float dpp_add(float x) {
    int s = __builtin_amdgcn_update_dpp(0, __builtin_bit_cast(int, x),
                                        CTRL, 0xF, 0xF, true);
    return x + __builtin_bit_cast(float, s);
}

// Wave64 sum -> uniform value via readlane 63. No DS-pipe ops.
__device__ __forceinline__ float wave_sum(float x) {
    x = dpp_add<0x111>(x);   // row_shr:1
    x = dpp_add<0x112>(x);   // row_shr:2
    x = dpp_add<0x114>(x);   // row_shr:4
    x = dpp_add<0x118>(x);   // row_shr:8
    x = dpp_add<0x142>(x);   // row_bcast:15
    x = dpp_add<0x143>(x);   // row_bcast:31 -> lane 63 holds total
    return __builtin_bit_cast(float,
        __builtin_amdgcn_readlane(__builtin_bit_cast(int, x), 63));
}

__device__ __forceinline__ float fast_sigmoid(float g) {
    return __builtin_amdgcn_rcpf(1.0f + __expf(-g));
}

__global__ void __launch_bounds__(TPB, 4) vsn_fused(
    const float* __restrict__ x,     // [N,32]
    const float* __restrict__ sgw,   // [32,64]
    const float* __restrict__ sgb,   // [64]
    const float* __restrict__ slg,   // [32]
    const float* __restrict__ slb,   // [32]
    const float* __restrict__ vgw,   // [32,512]
    const float* __restrict__ vgb,   // [32,512]
    const float* __restrict__ vsw,   // [32,256]
    const float* __restrict__ vsb,   // [32,256]
    const float* __restrict__ vlg,   // [32,256]
    const float* __restrict__ vlb,   // [32,256]
    float* __restrict__ out)         // [N,256]
{
    __shared__ float acc_s[RPB * ODIM];      // 16KB per-row output accumulators
    __shared__ float x_s[RPB][VDIM];         // 2KB
    __shared__ float g_s[RPB][2 * VDIM];     // 4KB
    __shared__ float w_s[RPB][VDIM];         // 2KB

    const int tid  = threadIdx.x;
    const int row0 = blockIdx.x * RPB;
    const int wave = tid >> 6;               // 0..15
    const int lane = tid & 63;
    const int v0   = wave * 2;               // this wave's two variables

    // ---- load this wave's weights (lane l owns cols l, l+64, l+128, l+192).
    // All indices compile-time; pinned below so they MUST stay in VGPRs.
    float ga[2][4], gb[2][4], va[2][4], vb[2][4];
    float sw[2][4], sb[2][4], lg[2][4], lb[2][4];
    #pragma unroll
    for (int j = 0; j < 2; ++j) {
        const int v = v0 + j;
        #pragma unroll
        for (int k = 0; k < 4; ++k) {
            const int c = lane + 64 * k;
            ga[j][k] = vgw[v * 512 + c];
            va[j][k] = vgw[v * 512 + 256 + c];
            gb[j][k] = vgb[v * 512 + c];
            vb[j][k] = vgb[v * 512 + 256 + c];
            sw[j][k] = vsw[v * 256 + c];
            sb[j][k] = vsb[v * 256 + c];
            lg[j][k] = vlg[v * 256 + c];
            lb[j][k] = vlb[v * 256 + c];
        }
    }

    // ---- zero the output accumulators ----
    *(float4*)(acc_s + (tid << 2)) = make_float4(0.f, 0.f, 0.f, 0.f);

    // ---- load x rows (16*32 = 512 floats) ----
    if (tid < RPB * VDIM)
        ((float*)x_s)[tid] = x[row0 * VDIM + tid];
    __syncthreads();

    // ---- Phase A1: g = x @ sel_gate_w + b (16 rows x 64 cols = 1024 tasks) ----
    {
        const int r = tid >> 6, j = tid & 63;
        float acc = sgb[j];
        #pragma unroll
        for (int v = 0; v < VDIM; ++v)
            acc = fmaf(x_s[r][v], sgw[v * 64 + j], acc);
        g_s[r][j] = acc;
    }
    __syncthreads();

    // ---- Phase A2: GLU -> +x -> LN(32) -> softmax(32) -> weights ----
    if (tid < RPB * VDIM) {
        const int r = tid >> 5, v = tid & 31;
        const float gate = g_s[r][v];
        const float val  = g_s[r][VDIM + v];
        const float y    = fast_sigmoid(gate) * val + x_s[r][v];
        float s1 = y, s2 = y * y;
        #pragma unroll
        for (int m = 1; m < 32; m <<= 1) {
            s1 += __shfl_xor(s1, m, 64);
            s2 += __shfl_xor(s2, m, 64);
        }
        const float mean = s1 * (1.0f / VDIM);
        const float var  = s2 * (1.0f / VDIM) - mean * mean;
        const float rs   = __builtin_amdgcn_rsqf(var + 1e-5f);
        const float sel  = slg[v] * ((y - mean) * rs) + slb[v];
        float mx = sel;
        #pragma unroll
        for (int m = 1; m < 32; m <<= 1)
            mx = fmaxf(mx, __shfl_xor(mx, m, 64));
        const float e = __expf(sel - mx);
        float se = e;
        #pragma unroll
        for (int m = 1; m < 32; m <<= 1)
            se += __shfl_xor(se, m, 64);
        w_s[r][v] = e * __builtin_amdgcn_rcpf(se);
    }
    __syncthreads();

    // ---- fold sigmoid into exp2 form: sig(g) = rcp(1 + 2^(-g*log2e)) ----
    constexpr float NL2E = -1.4426950408889634f;
    #pragma unroll
    for (int j = 0; j < 2; ++j)
        #pragma unroll
        for (int k = 0; k < 4; ++k) { ga[j][k] *= NL2E; gb[j][k] *= NL2E; }

    // ---- PIN the 64 weight values into VGPRs. The asm is opaque: the
    // compiler cannot rematerialize the loads past it, so the values stay
    // register-resident across the row loop (R8's failure mode).
    #pragma unroll
    for (int j = 0; j < 2; ++j)
        #pragma unroll
        for (int k = 0; k < 4; ++k)
            asm volatile("" : "+v"(ga[j][k]), "+v"(gb[j][k]),
                              "+v"(va[j][k]), "+v"(vb[j][k]),
                              "+v"(sw[j][k]), "+v"(sb[j][k]),
                              "+v"(lg[j][k]), "+v"(lb[j][k]));

    // ---- Phase B: loop rows, no barriers. Wave-staggered row order. ----
    for (int i = 0; i < RPB; ++i) {
        const int r  = (wave + i) & (RPB - 1);
        const float xa = x_s[r][v0];         // LDS broadcast reads
        const float xb = x_s[r][v0 + 1];
        const float wa = w_s[r][v0];
        const float wb = w_s[r][v0 + 1];

        float yA[4], yB[4];
        #pragma unroll
        for (int k = 0; k < 4; ++k) {
            const float eA = __builtin_amdgcn_exp2f(fmaf(xa, ga[0][k], gb[0][k]));
            const float sA = __builtin_amdgcn_rcpf(1.0f + eA);
            yA[k] = fmaf(sA, fmaf(xa, va[0][k], vb[0][k]), fmaf(xa, sw[0][k], sb[0][k]));
            const float eB = __builtin_amdgcn_exp2f(fmaf(xb, ga[1][k], gb[1][k]));
            const float sB = __builtin_amdgcn_rcpf(1.0f + eB);
            yB[k] = fmaf(sB, fmaf(xb, va[1][k], vb[1][k]), fmaf(xb, sw[1][k], sb[1][k]));
        }

        const float s1a = wave_sum((yA[0] + yA[1]) + (yA[2] + yA[3]));
        const float s2a = wave_sum(fmaf(yA[0], yA[0], fmaf(yA[1], yA[1],
                                   fmaf(yA[2], yA[2], yA[3] * yA[3]))));
        const float s1b = wave_sum((yB[0] + yB[1]) + (yB[2] + yB[3]));
        const float s2b = wave_sum(fmaf(yB[0], yB[0], fmaf(yB[1], yB[1],
                                   fmaf(yB[2], yB[2], yB[3] * yB[3]))));

        const float mA  = s1a * (1.0f / ODIM);
        const float vA  = s2a * (1.0f / ODIM) - mA * mA;
        const float rsA = __builtin_amdgcn_rsqf(vA + 1e-5f);
        const float wrsA = wa * rsA;
        const float mB  = s1b * (1.0f / ODIM);
        const float vB  = s2b * (1.0f / ODIM) - mB * mB;
        const float rsB = __builtin_amdgcn_rsqf(vB + 1e-5f);
        const float wrsB = wb * rsB;

        #pragma unroll
        for (int k = 0; k < 4; ++k) {
            const float c = fmaf(lg[0][k], (yA[k] - mA) * wrsA, wa * lb[0][k])
                          + fmaf(lg[1][k], (yB[k] - mB) * wrsB, wb * lb[1][k]);
            atomicAdd(&acc_s[r * ODIM + lane + 64 * k], c);  // ds_add_f32
        }
    }
    __syncthreads();

    // ---- epilogue: wave w writes row w ----
    const float4 o4 = *(const float4*)(acc_s + wave * ODIM + (lane << 2));
    *(float4*)(out + (size_t)(row0 + wave) * ODIM + (lane << 2)) = o4;
}

extern "C" void kernel_launch(void* const* d_in, const int* in_sizes, int n_in,
                              void* d_out, int out_size, void* d_ws, size_t ws_size,
                              hipStream_t stream) {
    const float* x   = (const float*)d_in[0];
    const float* sgw = (const float*)d_in[5];
    const float* sgb = (const float*)d_in[6];
    const float* slg = (const float*)d_in[7];
    const float* slb = (const float*)d_in[8];
    const float* vgw = (const float*)d_in[13];
    const float* vgb = (const float*)d_in[14];
    const float* vsw = (const float*)d_in[15];
    const float* vsb = (const float*)d_in[16];
    const float* vlg = (const float*)d_in[17];
    const float* vlb = (const float*)d_in[18];
    float* out = (float*)d_out;

    const int N = in_sizes[0] / VDIM;      // 4096 rows
    const int grid = N / RPB;              // 256 blocks, 1 per CU

    vsn_fused<<<grid, TPB, 0, stream>>>(x, sgw, sgb, slg, slb,
                                        vgw, vgb, vsw, vsb, vlg, vlb, out);
}

// Round 10
// 188.517 us; speedup vs baseline: 1.0364x; 1.0331x over previous
//
#include <hip/hip_runtime.h>
#include <hip/hip_bf16.h>

// VariableSelectionNetwork fused kernel, round 10.
//
// Live computation (sel fc1/fc2 and the nvh,vho einsum are dead in the ref):
//   weights = softmax(LN(GLU(x @ sel_gate_w + b) + x))            [N,32]
//   y[n,v,o] = sigmoid(x*gw+gb)*(x*gw'+gb') + (x*sw+sb)           [N,32,256]
//   out[n,o] = sum_v weights[n,v] * LN_o(y)[.,v,.]                [N,256]
//
// R8/R9 failure mechanism (finally isolated): LDS=24.5KB allows 2 blocks/CU
// -> scheduler targets 8 waves/SIMD -> 64-VGPR budget -> the 64 weight
// loads get sunk into the row loop (VGPR_Count=48, 1024 VMEM/thread,
// 106us). The asm pin couldn't stop it (pins at a point, not a range).
// R10: amdgpu_waves_per_eu(4,4) caps the occupancy target at 4 waves/SIMD
// -> 128-VGPR budget -> weights stay hoisted and register-resident.

#define VDIM 32
#define ODIM 256
#define RPB  16          // rows per block
#define TPB  1024        // 16 waves, 4/SIMD

// DPP-add: x += dpp_moved(x), 0-filled for invalid source lanes. Pure VALU.
template <int CTRL>
__device__ __forceinline__ float dpp_add(float x) {
    int s = __builtin_amdgcn_update_dpp(0, __builtin_bit_cast(int, x),
                                        CTRL, 0xF, 0xF, true);
    return x + __builtin_bit_cast(float, s);
}

// Wave64 sum -> uniform value via readlane 63. No DS-pipe ops.
__device__ __forceinline__ float wave_sum(float x) {
    x = dpp_add<0x111>(x);   // row_shr:1
    x = dpp_add<0x112>(x);   // row_shr:2
    x = dpp_add<0x114>(x);   // row_shr:4
    x = dpp_add<0x118>(x);   // row_shr:8
    x = dpp_add<0x142>(x);   // row_bcast:15
    x = dpp_add<0x143>(x);   // row_bcast:31 -> lane 63 holds total
    return __builtin_bit_cast(float,
        __builtin_amdgcn_readlane(__builtin_bit_cast(int, x), 63));
}

__device__ __forceinline__ float fast_sigmoid(float g) {
    return __builtin_amdgcn_rcpf(1.0f + __expf(-g));
}

__global__ void
__attribute__((amdgpu_flat_work_group_size(TPB, TPB), amdgpu_waves_per_eu(4, 4)))
vsn_fused(
    const float* __restrict__ x,     // [N,32]
    const float* __restrict__ sgw,   // [32,64]
    const float* __restrict__ sgb,   // [64]
    const float* __restrict__ slg,   // [32]
    const float* __restrict__ slb,   // [32]
    const float* __restrict__ vgw,   // [32,512]
    const float* __restrict__ vgb,   // [32,512]
    const float* __restrict__ vsw,   // [32,256]
    const float* __restrict__ vsb,   // [32,256]
    const float* __restrict__ vlg,   // [32,256]
    const float* __restrict__ vlb,   // [32,256]
    float* __restrict__ out)         // [N,256]
{
    __shared__ float acc_s[RPB * ODIM];      // 16KB per-row output accumulators
    __shared__ float x_s[RPB][VDIM];         // 2KB
    __shared__ float g_s[RPB][2 * VDIM];     // 4KB
    __shared__ float w_s[RPB][VDIM];         // 2KB

    const int tid  = threadIdx.x;
    const int row0 = blockIdx.x * RPB;
    const int wave = tid >> 6;               // 0..15
    const int lane = tid & 63;
    const int v0   = wave * 2;               // this wave's two variables

    // ---- load this wave's weights (lane l owns cols l, l+64, l+128, l+192).
    // All indices compile-time; with the 128-VGPR budget these stay hoisted.
    float ga[2][4], gb[2][4], va[2][4], vb[2][4];
    float sw[2][4], sb[2][4], lg[2][4], lb[2][4];
    #pragma unroll
    for (int j = 0; j < 2; ++j) {
        const int v = v0 + j;
        #pragma unroll
        for (int k = 0; k < 4; ++k) {
            const int c = lane + 64 * k;
            ga[j][k] = vgw[v * 512 + c];
            va[j][k] = vgw[v * 512 + 256 + c];
            gb[j][k] = vgb[v * 512 + c];
            vb[j][k] = vgb[v * 512 + 256 + c];
            sw[j][k] = vsw[v * 256 + c];
            sb[j][k] = vsb[v * 256 + c];
            lg[j][k] = vlg[v * 256 + c];
            lb[j][k] = vlb[v * 256 + c];
        }
    }

    // ---- zero the output accumulators ----
    *(float4*)(acc_s + (tid << 2)) = make_float4(0.f, 0.f, 0.f, 0.f);

    // ---- load x rows (16*32 = 512 floats) ----
    if (tid < RPB * VDIM)
        ((float*)x_s)[tid] = x[row0 * VDIM + tid];
    __syncthreads();

    // ---- Phase A1: g = x @ sel_gate_w + b (16 rows x 64 cols = 1024 tasks) ----
    {
        const int r = tid >> 6, j = tid & 63;
        float acc = sgb[j];
        #pragma unroll
        for (int v = 0; v < VDIM; ++v)
            acc = fmaf(x_s[r][v], sgw[v * 64 + j], acc);
        g_s[r][j] = acc;
    }
    __syncthreads();

    // ---- Phase A2: GLU -> +x -> LN(32) -> softmax(32) -> weights ----
    if (tid < RPB * VDIM) {
        const int r = tid >> 5, v = tid & 31;
        const float gate = g_s[r][v];
        const float val  = g_s[r][VDIM + v];
        const float y    = fast_sigmoid(gate) * val + x_s[r][v];
        float s1 = y, s2 = y * y;
        #pragma unroll
        for (int m = 1; m < 32; m <<= 1) {
            s1 += __shfl_xor(s1, m, 64);
            s2 += __shfl_xor(s2, m, 64);
        }
        const float mean = s1 * (1.0f / VDIM);
        const float var  = s2 * (1.0f / VDIM) - mean * mean;
        const float rs   = __builtin_amdgcn_rsqf(var + 1e-5f);
        const float sel  = slg[v] * ((y - mean) * rs) + slb[v];
        float mx = sel;
        #pragma unroll
        for (int m = 1; m < 32; m <<= 1)
            mx = fmaxf(mx, __shfl_xor(mx, m, 64));
        const float e = __expf(sel - mx);
        float se = e;
        #pragma unroll
        for (int m = 1; m < 32; m <<= 1)
            se += __shfl_xor(se, m, 64);
        w_s[r][v] = e * __builtin_amdgcn_rcpf(se);
    }
    __syncthreads();

    // ---- fold sigmoid into exp2 form: sig(g) = rcp(1 + 2^(-g*log2e)) ----
    constexpr float NL2E = -1.4426950408889634f;
    #pragma unroll
    for (int j = 0; j < 2; ++j)
        #pragma unroll
        for (int k = 0; k < 4; ++k) { ga[j][k] *= NL2E; gb[j][k] *= NL2E; }

    // ---- backstop pin (harmless if hoisting already holds) ----
    #pragma unroll
    for (int j = 0; j < 2; ++j)
        #pragma unroll
        for (int k = 0; k < 4; ++k)
            asm volatile("" : "+v"(ga[j][k]), "+v"(gb[j][k]),
                              "+v"(va[j][k]), "+v"(vb[j][k]),
                              "+v"(sw[j][k]), "+v"(sb[j][k]),
                              "+v"(lg[j][k]), "+v"(lb[j][k]));

    // ---- Phase B: loop rows, no barriers. Wave-staggered row order keeps
    // the 16 waves on 16 distinct rows at each step (atomicAdd correct
    // regardless; stagger just avoids same-address serialization). ----
    for (int i = 0; i < RPB; ++i) {
        const int r  = (wave + i) & (RPB - 1);
        const float xa = x_s[r][v0];         // LDS broadcast reads
        const float xb = x_s[r][v0 + 1];
        const float wa = w_s[r][v0];
        const float wb = w_s[r][v0 + 1];

        float yA[4], yB[4];
        #pragma unroll
        for (int k = 0; k < 4; ++k) {
            const float eA = __builtin_amdgcn_exp2f(fmaf(xa, ga[0][k], gb[0][k]));
            const float sA = __builtin_amdgcn_rcpf(1.0f + eA);
            yA[k] = fmaf(sA, fmaf(xa, va[0][k], vb[0][k]), fmaf(xa, sw[0][k], sb[0][k]));
            const float eB = __builtin_amdgcn_exp2f(fmaf(xb, ga[1][k], gb[1][k]));
            const float sB = __builtin_amdgcn_rcpf(1.0f + eB);
            yB[k] = fmaf(sB, fmaf(xb, va[1][k], vb[1][k]), fmaf(xb, sw[1][k], sb[1][k]));
        }

        const float s1a = wave_sum((yA[0] + yA[1]) + (yA[2] + yA[3]));
        const float s2a = wave_sum(fmaf(yA[0], yA[0], fmaf(yA[1], yA[1],
                                   fmaf(yA[2], yA[2], yA[3] * yA[3]))));
        const float s1b = wave_sum((yB[0] + yB[1]) + (yB[2] + yB[3]));
        const float s2b = wave_sum(fmaf(yB[0], yB[0], fmaf(yB[1], yB[1],
                                   fmaf(yB[2], yB[2], yB[3] * yB[3]))));

        const float mA  = s1a * (1.0f / ODIM);
        const float vA  = s2a * (1.0f / ODIM) - mA * mA;
        const float rsA = __builtin_amdgcn_rsqf(vA + 1e-5f);
        const float wrsA = wa * rsA;
        const float mB  = s1b * (1.0f / ODIM);
        const float vB  = s2b * (1.0f / ODIM) - mB * mB;
        const float rsB = __builtin_amdgcn_rsqf(vB + 1e-5f);
        const float wrsB = wb * rsB;

        #pragma unroll
        for (int k = 0; k < 4; ++k) {
            const float c = fmaf(lg[0][k], (yA[k] - mA) * wrsA, wa * lb[0][k])
                          + fmaf(lg[1][k], (yB[k] - mB) * wrsB, wb * lb[1][k]);
            atomicAdd(&acc_s[r * ODIM + lane + 64 * k], c);  // ds_add_f32
        }
    }
    __syncthreads();

    // ---- epilogue: wave w writes row w ----
    const float4 o4 = *(const float4*)(acc_s + wave * ODIM + (lane << 2));
    *(float4*)(out + (size_t)(row0 + wave) * ODIM + (lane << 2)) = o4;
}

extern "C" void kernel_launch(void* const* d_in, const int* in_sizes, int n_in,
                              void* d_out, int out_size, void* d_ws, size_t ws_size,
                              hipStream_t stream) {
    const float* x   = (const float*)d_in[0];
    const float* sgw = (const float*)d_in[5];
    const float* sgb = (const float*)d_in[6];
    const float* slg = (const float*)d_in[7];
    const float* slb = (const float*)d_in[8];
    const float* vgw = (const float*)d_in[13];
    const float* vgb = (const float*)d_in[14];
    const float* vsw = (const float*)d_in[15];
    const float* vsb = (const float*)d_in[16];
    const float* vlg = (const float*)d_in[17];
    const float* vlb = (const float*)d_in[18];
    float* out = (float*)d_out;

    const int N = in_sizes[0] / VDIM;      // 4096 rows
    const int grid = N / RPB;              // 256 blocks, 1 per CU

    vsn_fused<<<grid, TPB, 0, stream>>>(x, sgw, sgb, slg, slb,
                                        vgw, vgb, vsw, vsb, vlg, vlb, out);
}

// Round 11
// 133.903 us; speedup vs baseline: 1.4591x; 1.4079x over previous
//
#include <hip/hip_runtime.h>
#include <hip/hip_bf16.h>

// VariableSelectionNetwork fused kernel, round 11.
//
// Live computation (sel fc1/fc2 and the nvh,vho einsum are dead in the ref):
//   weights = softmax(LN(GLU(x @ sel_gate_w + b) + x))            [N,32]
//   y[n,v,o] = sigmoid(x*gw+gb)*(x*gw'+gb') + (x*sw+sb)           [N,32,256]
//   out[n,o] = sum_v weights[n,v] * LN_o(y)[.,v,.]                [N,256]
//
// History: R4-R7 (LDS chunk-staged fp32 weights, barrier per chunk) ~30us —
// stalls on barriers + redundant DS reads. R8-R10 (register-resident
// weights) defeated by compiler load-sinking (VGPR pinned ~48-56).
// R11: ENTIRE weight set in LDS as bf16 (128KB fits; fp32's 256KB doesn't).
// One staging pass + one barrier, then a barrier-free v-loop with no
// global traffic and no atomics. Wave owns rows 2w,2w+1 (one weight read
// serves two rows). Sigmoid exp2-folded at staging (gate arrays pre-scaled
// by -log2e). LDS-capped occupancy (1 block/CU) => VGPR budget can't bind.

#define VDIM 32
#define ODIM 256
#define RPB  16          // rows per block
#define TPB  512         // 8 waves; wave w owns rows 2w, 2w+1
#define NL2E (-1.4426950408889634f)

// DPP-add: x += dpp_moved(x), 0-filled for invalid source lanes. Pure VALU.
template <int CTRL>
__device__ __forceinline__ float dpp_add(float x) {
    int s = __builtin_amdgcn_update_dpp(0, __builtin_bit_cast(int, x),
                                        CTRL, 0xF, 0xF, true);
    return x + __builtin_bit_cast(float, s);
}

// Wave64 sum -> uniform value via readlane 63. No DS-pipe ops.
__device__ __forceinline__ float wave_sum(float x) {
    x = dpp_add<0x111>(x);   // row_shr:1
    x = dpp_add<0x112>(x);   // row_shr:2
    x = dpp_add<0x114>(x);   // row_shr:4
    x = dpp_add<0x118>(x);   // row_shr:8
    x = dpp_add<0x142>(x);   // row_bcast:15
    x = dpp_add<0x143>(x);   // row_bcast:31 -> lane 63 holds total
    return __builtin_bit_cast(float,
        __builtin_amdgcn_readlane(__builtin_bit_cast(int, x), 63));
}

__device__ __forceinline__ float fast_sigmoid(float g) {
    return __builtin_amdgcn_rcpf(1.0f + __expf(-g));
}

// fp32 -> bf16 round-to-nearest-even (result in low 16 bits)
__device__ __forceinline__ unsigned bf16rne(float f) {
    unsigned u = __builtin_bit_cast(unsigned, f);
    return (u + 0x7FFFu + ((u >> 16) & 1u)) >> 16;
}
__device__ __forceinline__ unsigned pack2(float lo, float hi) {
    return bf16rne(lo) | (bf16rne(hi) << 16);
}

#define BFLO(u) __builtin_bit_cast(float, (u) << 16)
#define BFHI(u) __builtin_bit_cast(float, (u) & 0xFFFF0000u)

__global__ void __launch_bounds__(TPB) vsn_fused(
    const float* __restrict__ x,     // [N,32]
    const float* __restrict__ sgw,   // [32,64]
    const float* __restrict__ sgb,   // [64]
    const float* __restrict__ slg,   // [32]
    const float* __restrict__ slb,   // [32]
    const float* __restrict__ vgw,   // [32,512]
    const float* __restrict__ vgb,   // [32,512]
    const float* __restrict__ vsw,   // [32,256]
    const float* __restrict__ vsb,   // [32,256]
    const float* __restrict__ vlg,   // [32,256]
    const float* __restrict__ vlb,   // [32,256]
    float* __restrict__ out)         // [N,256]
{
    // Weight image: per v (32), 8 arrays x 256 o in bf16 = 4KB/v = 128KB.
    // ushort index (v,a,o) = v*2048 + a*256 + o. Arrays:
    // a0 gate_w*NL2E | a1 value_w | a2 gate_b*NL2E | a3 value_b
    // a4 skip_w | a5 skip_b | a6 ln_g | a7 ln_b
    __shared__ unsigned short wlds[32 * 2048];   // 128KB
    __shared__ float2 xw_s[RPB][VDIM];           // .x = x, .y = softmax weight (4KB)
    __shared__ float  g_s[RPB][2 * VDIM];        // 4KB

    const int tid  = threadIdx.x;
    const int row0 = blockIdx.x * RPB;

    // ---- load x rows (16*32 = 512 = TPB) ----
    xw_s[tid >> 5][tid & 31].x = x[row0 * VDIM + tid];

    // ---- stage all weights to LDS as bf16 (once; gate arrays pre-scaled) ----
    {
        const int r = tid >> 1, h = tid & 1;     // r: (v,a) pair, h: 128-o half
        const int v = r >> 3, a = r & 7;
        const float* src;
        if (a == 0)      src = vgw + v * 512;
        else if (a == 1) src = vgw + v * 512 + 256;
        else if (a == 2) src = vgb + v * 512;
        else if (a == 3) src = vgb + v * 512 + 256;
        else if (a == 4) src = vsw + v * 256;
        else if (a == 5) src = vsb + v * 256;
        else if (a == 6) src = vlg + v * 256;
        else             src = vlb + v * 256;
        src += h * 128;
        const float scale = (a == 0 || a == 2) ? NL2E : 1.0f;
        unsigned short* dst = wlds + v * 2048 + a * 256 + h * 128;
        #pragma unroll 4
        for (int i = 0; i < 16; ++i) {           // 8 values / iter
            const float4 f0 = *(const float4*)(src + i * 8);
            const float4 f1 = *(const float4*)(src + i * 8 + 4);
            uint4 p;
            p.x = pack2(f0.x * scale, f0.y * scale);
            p.y = pack2(f0.z * scale, f0.w * scale);
            p.z = pack2(f1.x * scale, f1.y * scale);
            p.w = pack2(f1.z * scale, f1.w * scale);
            *(uint4*)(dst + i * 8) = p;
        }
    }
    __syncthreads();

    // ---- Phase A1: g = x @ sel_gate_w + b (16 rows x 64 cols, 2 tasks/thread) ----
    #pragma unroll
    for (int it = 0; it < 2; ++it) {
        const int i = tid + it * TPB;
        const int r = i >> 6, j = i & 63;
        float acc = sgb[j];
        #pragma unroll
        for (int v = 0; v < VDIM; ++v)
            acc = fmaf(xw_s[r][v].x, sgw[v * 64 + j], acc);
        g_s[r][j] = acc;
    }
    __syncthreads();

    // ---- Phase A2: GLU -> +x -> LN(32) -> softmax(32) -> weights (512 tasks) ----
    {
        const int r = tid >> 5, v = tid & 31;
        const float gate = g_s[r][v];
        const float val  = g_s[r][VDIM + v];
        const float y    = fast_sigmoid(gate) * val + xw_s[r][v].x;
        float s1 = y, s2 = y * y;
        #pragma unroll
        for (int m = 1; m < 32; m <<= 1) {
            s1 += __shfl_xor(s1, m, 64);
            s2 += __shfl_xor(s2, m, 64);
        }
        const float mean = s1 * (1.0f / VDIM);
        const float var  = s2 * (1.0f / VDIM) - mean * mean;
        const float rs   = __builtin_amdgcn_rsqf(var + 1e-5f);
        const float sel  = slg[v] * ((y - mean) * rs) + slb[v];
        float mx = sel;
        #pragma unroll
        for (int m = 1; m < 32; m <<= 1)
            mx = fmaxf(mx, __shfl_xor(mx, m, 64));
        const float e = __expf(sel - mx);
        float se = e;
        #pragma unroll
        for (int m = 1; m < 32; m <<= 1)
            se += __shfl_xor(se, m, 64);
        xw_s[r][v].y = e * __builtin_amdgcn_rcpf(se);
    }
    __syncthreads();

    // ---- Phase B: barrier-free. Wave owns rows rA=2w, rB=2w+1; lane owns
    // o-quad [4l,4l+3]. All weight reads are conflict-free ds_read_b64. ----
    const int wave = tid >> 6;
    const int lane = tid & 63;
    const int o0   = lane << 2;
    const int rA   = wave * 2, rB = rA + 1;

    float aA0 = 0.f, aA1 = 0.f, aA2 = 0.f, aA3 = 0.f;
    float aB0 = 0.f, aB1 = 0.f, aB2 = 0.f, aB3 = 0.f;

    #pragma unroll 2
    for (int v = 0; v < VDIM; ++v) {
        const unsigned short* wv = wlds + v * 2048 + o0;
        const uint2 Ugw = *(const uint2*)(wv);
        const uint2 Uvw = *(const uint2*)(wv + 256);
        const uint2 Ugb = *(const uint2*)(wv + 512);
        const uint2 Uvb = *(const uint2*)(wv + 768);
        const uint2 Usw = *(const uint2*)(wv + 1024);
        const uint2 Usb = *(const uint2*)(wv + 1280);
        const uint2 Ulg = *(const uint2*)(wv + 1536);
        const uint2 Ulb = *(const uint2*)(wv + 1792);
        const float2 XA = xw_s[rA][v];      // broadcast b64
        const float2 XB = xw_s[rB][v];
        const float xa = XA.x, wa = XA.y, xb = XB.x, wb = XB.y;

        const float gw0 = BFLO(Ugw.x), gw1 = BFHI(Ugw.x), gw2 = BFLO(Ugw.y), gw3 = BFHI(Ugw.y);
        const float vw0 = BFLO(Uvw.x), vw1 = BFHI(Uvw.x), vw2 = BFLO(Uvw.y), vw3 = BFHI(Uvw.y);
        const float gb0 = BFLO(Ugb.x), gb1 = BFHI(Ugb.x), gb2 = BFLO(Ugb.y), gb3 = BFHI(Ugb.y);
        const float vb0 = BFLO(Uvb.x), vb1 = BFHI(Uvb.x), vb2 = BFLO(Uvb.y), vb3 = BFHI(Uvb.y);
        const float sw0 = BFLO(Usw.x), sw1 = BFHI(Usw.x), sw2 = BFLO(Usw.y), sw3 = BFHI(Usw.y);
        const float sb0 = BFLO(Usb.x), sb1 = BFHI(Usb.x), sb2 = BFLO(Usb.y), sb3 = BFHI(Usb.y);
        const float lg0 = BFLO(Ulg.x), lg1 = BFHI(Ulg.x), lg2 = BFLO(Ulg.y), lg3 = BFHI(Ulg.y);
        const float lb0 = BFLO(Ulb.x), lb1 = BFHI(Ulb.x), lb2 = BFLO(Ulb.y), lb3 = BFHI(Ulb.y);

        // sig(g) = rcp(1 + exp2(g*gw_scaled + gb_scaled))  [gate pre-scaled by -log2e]
        #define YV(xr, k) fmaf(__builtin_amdgcn_rcpf(1.0f + \
            __builtin_amdgcn_exp2f(fmaf(xr, gw##k, gb##k))), \
            fmaf(xr, vw##k, vb##k), fmaf(xr, sw##k, sb##k))
        const float yA0 = YV(xa, 0), yA1 = YV(xa, 1), yA2 = YV(xa, 2), yA3 = YV(xa, 3);
        const float yB0 = YV(xb, 0), yB1 = YV(xb, 1), yB2 = YV(xb, 2), yB3 = YV(xb, 3);
        #undef YV

        const float s1a = wave_sum((yA0 + yA1) + (yA2 + yA3));
        const float s2a = wave_sum(fmaf(yA0, yA0, fmaf(yA1, yA1, fmaf(yA2, yA2, yA3 * yA3))));
        const float s1b = wave_sum((yB0 + yB1) + (yB2 + yB3));
        const float s2b = wave_sum(fmaf(yB0, yB0, fmaf(yB1, yB1, fmaf(yB2, yB2, yB3 * yB3))));

        const float mA  = s1a * (1.0f / ODIM);
        const float vA  = s2a * (1.0f / ODIM) - mA * mA;
        const float rsA = __builtin_amdgcn_rsqf(vA + 1e-5f);
        const float wrsA = wa * rsA;
        aA0 = fmaf(lg0, (yA0 - mA) * wrsA, fmaf(wa, lb0, aA0));
        aA1 = fmaf(lg1, (yA1 - mA) * wrsA, fmaf(wa, lb1, aA1));
        aA2 = fmaf(lg2, (yA2 - mA) * wrsA, fmaf(wa, lb2, aA2));
        aA3 = fmaf(lg3, (yA3 - mA) * wrsA, fmaf(wa, lb3, aA3));

        const float mB  = s1b * (1.0f / ODIM);
        const float vB  = s2b * (1.0f / ODIM) - mB * mB;
        const float rsB = __builtin_amdgcn_rsqf(vB + 1e-5f);
        const float wrsB = wb * rsB;
        aB0 = fmaf(lg0, (yB0 - mB) * wrsB, fmaf(wb, lb0, aB0));
        aB1 = fmaf(lg1, (yB1 - mB) * wrsB, fmaf(wb, lb1, aB1));
        aB2 = fmaf(lg2, (yB2 - mB) * wrsB, fmaf(wb, lb2, aB2));
        aB3 = fmaf(lg3, (yB3 - mB) * wrsB, fmaf(wb, lb3, aB3));
    }

    *(float4*)(out + (size_t)(row0 + rA) * ODIM + o0) = make_float4(aA0, aA1, aA2, aA3);
    *(float4*)(out + (size_t)(row0 + rB) * ODIM + o0) = make_float4(aB0, aB1, aB2, aB3);
}

extern "C" void kernel_launch(void* const* d_in, const int* in_sizes, int n_in,
                              void* d_out, int out_size, void* d_ws, size_t ws_size,
                              hipStream_t stream) {
    const float* x   = (const float*)d_in[0];
    const float* sgw = (const float*)d_in[5];
    const float* sgb = (const float*)d_in[6];
    const float* slg = (const float*)d_in[7];
    const float* slb = (const float*)d_in[8];
    const float* vgw = (const float*)d_in[13];
    const float* vgb = (const float*)d_in[14];
    const float* vsw = (const float*)d_in[15];
    const float* vsb = (const float*)d_in[16];
    const float* vlg = (const float*)d_in[17];
    const float* vlb = (const float*)d_in[18];
    float* out = (float*)d_out;

    const int N = in_sizes[0] / VDIM;      // 4096 rows
    const int grid = N / RPB;              // 256 blocks, 1 per CU

    vsn_fused<<<grid, TPB, 0, stream>>>(x, sgw, sgb, slg, slb,
                                        vgw, vgb, vsw, vsb, vlg, vlb, out);
}

// Round 12
// 124.131 us; speedup vs baseline: 1.5740x; 1.0787x over previous
//
#include <hip/hip_runtime.h>
#include <hip/hip_bf16.h>

// VariableSelectionNetwork fused kernel, round 12.
//
// Live computation (sel fc1/fc2 and the nvh,vho einsum are dead in the ref):
//   weights = softmax(LN(GLU(x @ sel_gate_w + b) + x))            [N,32]
//   y[n,v,o] = sigmoid(x*gw+gb)*(x*gw'+gb') + (x*sw+sb)           [N,32,256]
//   out[n,o] = sum_v weights[n,v] * LN_o(y)[.,v,.]                [N,256]
//
// R11 (bf16 weights fully LDS-resident, barrier-free v-loop) hit 43.5us with
// 8.1M LDS bank conflicts (segment-serial staging writes: all 64 lanes of a
// wave hit the same 4 banks) and 20 addressed ds_read_b64 per v-pair.
// R12: (1) linear staging map (lane-consecutive 16B -> conflict-free),
// (2) v-pair-packed u32 words {bf16 v0, bf16 v1} -> 8 ds_read_b128 + 2
// broadcast b128 per pair (halves DS instrs + addressing VALU),
// (3) x/w packed float4 per (row,pair).

#define VDIM 32
#define ODIM 256
#define RPB  16          // rows per block
#define TPB  512         // 8 waves; wave w owns rows 2w, 2w+1
#define NL2E (-1.4426950408889634f)

// DPP-add: x += dpp_moved(x), 0-filled for invalid source lanes. Pure VALU.
template <int CTRL>
__device__ __forceinline__ float dpp_add(float x) {
    int s = __builtin_amdgcn_update_dpp(0, __builtin_bit_cast(int, x),
                                        CTRL, 0xF, 0xF, true);
    return x + __builtin_bit_cast(float, s);
}

// Wave64 sum -> uniform value via readlane 63. No DS-pipe ops.
__device__ __forceinline__ float wave_sum(float x) {
    x = dpp_add<0x111>(x);   // row_shr:1
    x = dpp_add<0x112>(x);   // row_shr:2
    x = dpp_add<0x114>(x);   // row_shr:4
    x = dpp_add<0x118>(x);   // row_shr:8
    x = dpp_add<0x142>(x);   // row_bcast:15
    x = dpp_add<0x143>(x);   // row_bcast:31 -> lane 63 holds total
    return __builtin_bit_cast(float,
        __builtin_amdgcn_readlane(__builtin_bit_cast(int, x), 63));
}

__device__ __forceinline__ float fast_sigmoid(float g) {
    return __builtin_amdgcn_rcpf(1.0f + __expf(-g));
}

// fp32 -> bf16 round-to-nearest-even (result in low 16 bits)
__device__ __forceinline__ unsigned bf16rne(float f) {
    unsigned u = __builtin_bit_cast(unsigned, f);
    return (u + 0x7FFFu + ((u >> 16) & 1u)) >> 16;
}
// word = {lo: bf16(a) [variable 2p], hi: bf16(b) [variable 2p+1]}
__device__ __forceinline__ unsigned packvv(float a, float b) {
    return bf16rne(a) | (bf16rne(b) << 16);
}

#define BFLO(u) __builtin_bit_cast(float, (u) << 16)
#define BFHI(u) __builtin_bit_cast(float, (u) & 0xFFFF0000u)

__global__ void __launch_bounds__(TPB) vsn_fused(
    const float* __restrict__ x,     // [N,32]
    const float* __restrict__ sgw,   // [32,64]
    const float* __restrict__ sgb,   // [64]
    const float* __restrict__ slg,   // [32]
    const float* __restrict__ slb,   // [32]
    const float* __restrict__ vgw,   // [32,512]
    const float* __restrict__ vgb,   // [32,512]
    const float* __restrict__ vsw,   // [32,256]
    const float* __restrict__ vsb,   // [32,256]
    const float* __restrict__ vlg,   // [32,256]
    const float* __restrict__ vlb,   // [32,256]
    float* __restrict__ out)         // [N,256]
{
    // Weight image: u32 word W[p][a][o] = {bf16 arr[2p][a][o], bf16 arr[2p+1][a][o]}
    // p in [0,16) v-pairs, a in [0,8) arrays, o in [0,256). 32768 u32 = 128KB.
    // Arrays: a0 gate_w*NL2E | a1 value_w | a2 gate_b*NL2E | a3 value_b
    //         a4 skip_w | a5 skip_b | a6 ln_g | a7 ln_b
    __shared__ unsigned wlds[16 * 2048];         // 128KB
    __shared__ float4 xw_s[RPB][16];             // {x0,w0,x1,w1} per (row,pair) 4KB
    __shared__ float  g_s[RPB][2 * VDIM];        // 4KB

    const int tid  = threadIdx.x;
    const int row0 = blockIdx.x * RPB;

    // ---- load x rows (16*32 = 512 = TPB) ----
    {
        const int r = tid >> 5, v = tid & 31;
        ((float*)&xw_s[r][v >> 1])[(v & 1) << 1] = x[row0 * VDIM + tid];
    }

    // ---- stage all weights to LDS, linear chunk map (conflict-free) ----
    // chunk c = k*TPB + tid covers u32 [4c, 4c+4): p = c>>9, a = (c>>6)&7,
    // o = (c&63)*4. Wave-uniform (p,a) per iteration (64 chunks per segment).
    #pragma unroll
    for (int k = 0; k < 16; ++k) {
        const int c = k * TPB + tid;
        const int p = c >> 9;
        const int a = (c >> 6) & 7;
        const int o = (c & 63) << 2;
        const int vA = p * 2, vB = vA + 1;
        const float* sA;
        const float* sB;
        if (a == 0)      { sA = vgw + vA * 512;       sB = vgw + vB * 512; }
        else if (a == 1) { sA = vgw + vA * 512 + 256; sB = vgw + vB * 512 + 256; }
        else if (a == 2) { sA = vgb + vA * 512;       sB = vgb + vB * 512; }
        else if (a == 3) { sA = vgb + vA * 512 + 256; sB = vgb + vB * 512 + 256; }
        else if (a == 4) { sA = vsw + vA * 256;       sB = vsw + vB * 256; }
        else if (a == 5) { sA = vsb + vA * 256;       sB = vsb + vB * 256; }
        else if (a == 6) { sA = vlg + vA * 256;       sB = vlg + vB * 256; }
        else             { sA = vlb + vA * 256;       sB = vlb + vB * 256; }
        const float4 fA = *(const float4*)(sA + o);
        const float4 fB = *(const float4*)(sB + o);
        const float s = (a == 0 || a == 2) ? NL2E : 1.0f;
        uint4 P;
        P.x = packvv(fA.x * s, fB.x * s);
        P.y = packvv(fA.y * s, fB.y * s);
        P.z = packvv(fA.z * s, fB.z * s);
        P.w = packvv(fA.w * s, fB.w * s);
        ((uint4*)wlds)[c] = P;
    }
    __syncthreads();

    // ---- Phase A1: g = x @ sel_gate_w + b (16 rows x 64 cols, 2 tasks/thread) ----
    #pragma unroll
    for (int it = 0; it < 2; ++it) {
        const int i = tid + it * TPB;
        const int r = i >> 6, j = i & 63;
        float acc = sgb[j];
        #pragma unroll
        for (int v = 0; v < VDIM; ++v)
            acc = fmaf(((const float*)&xw_s[r][v >> 1])[(v & 1) << 1],
                       sgw[v * 64 + j], acc);
        g_s[r][j] = acc;
    }
    __syncthreads();

    // ---- Phase A2: GLU -> +x -> LN(32) -> softmax(32) -> weights (512 tasks) ----
    {
        const int r = tid >> 5, v = tid & 31;
        const float xv   = ((const float*)&xw_s[r][v >> 1])[(v & 1) << 1];
        const float gate = g_s[r][v];
        const float val  = g_s[r][VDIM + v];
        const float y    = fast_sigmoid(gate) * val + xv;
        float s1 = y, s2 = y * y;
        #pragma unroll
        for (int m = 1; m < 32; m <<= 1) {
            s1 += __shfl_xor(s1, m, 64);
            s2 += __shfl_xor(s2, m, 64);
        }
        const float mean = s1 * (1.0f / VDIM);
        const float var  = s2 * (1.0f / VDIM) - mean * mean;
        const float rs   = __builtin_amdgcn_rsqf(var + 1e-5f);
        const float sel  = slg[v] * ((y - mean) * rs) + slb[v];
        float mx = sel;
        #pragma unroll
        for (int m = 1; m < 32; m <<= 1)
            mx = fmaxf(mx, __shfl_xor(mx, m, 64));
        const float e = __expf(sel - mx);
        float se = e;
        #pragma unroll
        for (int m = 1; m < 32; m <<= 1)
            se += __shfl_xor(se, m, 64);
        ((float*)&xw_s[r][v >> 1])[((v & 1) << 1) + 1] =
            e * __builtin_amdgcn_rcpf(se);
    }
    __syncthreads();

    // ---- Phase B: barrier-free pair loop. Wave owns rows rA=2w, rB=2w+1;
    // lane owns o-quad [4l,4l+3]. 8 ds_read_b128 (weights, imm offsets) +
    // 2 broadcast b128 (x/w) per pair. ----
    const int wave = tid >> 6;
    const int lane = tid & 63;
    const int o0   = lane << 2;
    const int rA   = wave * 2, rB = rA + 1;

    float aA0 = 0.f, aA1 = 0.f, aA2 = 0.f, aA3 = 0.f;
    float aB0 = 0.f, aB1 = 0.f, aB2 = 0.f, aB3 = 0.f;

    for (int p = 0; p < 16; ++p) {
        const unsigned* wv = wlds + (p << 11) + o0;   // one base; arrays at +a*256
        const uint4 Ugw = *(const uint4*)(wv);
        const uint4 Uvw = *(const uint4*)(wv + 256);
        const uint4 Ugb = *(const uint4*)(wv + 512);
        const uint4 Uvb = *(const uint4*)(wv + 768);
        const uint4 Usw = *(const uint4*)(wv + 1024);
        const uint4 Usb = *(const uint4*)(wv + 1280);
        const uint4 Ulg = *(const uint4*)(wv + 1536);
        const uint4 Ulb = *(const uint4*)(wv + 1792);
        const float4 XA = xw_s[rA][p];   // {x0,w0,x1,w1} broadcast
        const float4 XB = xw_s[rB][p];

        // y[row][j][k]: row in {A,B}, j = variable within pair, k = o-quad idx
        float yA[2][4], yB[2][4];
        #define UW(U, k) ((k) == 0 ? U.x : (k) == 1 ? U.y : (k) == 2 ? U.z : U.w)
        #pragma unroll
        for (int k = 0; k < 4; ++k) {
            const unsigned ugw = UW(Ugw, k), uvw = UW(Uvw, k), ugb = UW(Ugb, k),
                           uvb = UW(Uvb, k), usw = UW(Usw, k), usb = UW(Usb, k);
            // j=0 (lo halves)
            {
                const float gw = BFLO(ugw), vw = BFLO(uvw), gb = BFLO(ugb),
                            vb = BFLO(uvb), sw = BFLO(usw), sb = BFLO(usb);
                const float sgA = __builtin_amdgcn_rcpf(
                    1.0f + __builtin_amdgcn_exp2f(fmaf(XA.x, gw, gb)));
                yA[0][k] = fmaf(sgA, fmaf(XA.x, vw, vb), fmaf(XA.x, sw, sb));
                const float sgB = __builtin_amdgcn_rcpf(
                    1.0f + __builtin_amdgcn_exp2f(fmaf(XB.x, gw, gb)));
                yB[0][k] = fmaf(sgB, fmaf(XB.x, vw, vb), fmaf(XB.x, sw, sb));
            }
            // j=1 (hi halves)
            {
                const float gw = BFHI(ugw), vw = BFHI(uvw), gb = BFHI(ugb),
                            vb = BFHI(uvb), sw = BFHI(usw), sb = BFHI(usb);
                const float sgA = __builtin_amdgcn_rcpf(
                    1.0f + __builtin_amdgcn_exp2f(fmaf(XA.z, gw, gb)));
                yA[1][k] = fmaf(sgA, fmaf(XA.z, vw, vb), fmaf(XA.z, sw, sb));
                const float sgB = __builtin_amdgcn_rcpf(
                    1.0f + __builtin_amdgcn_exp2f(fmaf(XB.z, gw, gb)));
                yB[1][k] = fmaf(sgB, fmaf(XB.z, vw, vb), fmaf(XB.z, sw, sb));
            }
        }

        // 8 interleaved wave-sum chains (good DPP ILP)
        const float s1A0 = wave_sum((yA[0][0] + yA[0][1]) + (yA[0][2] + yA[0][3]));
        const float s2A0 = wave_sum(fmaf(yA[0][0], yA[0][0], fmaf(yA[0][1], yA[0][1],
                                    fmaf(yA[0][2], yA[0][2], yA[0][3] * yA[0][3]))));
        const float s1A1 = wave_sum((yA[1][0] + yA[1][1]) + (yA[1][2] + yA[1][3]));
        const float s2A1 = wave_sum(fmaf(yA[1][0], yA[1][0], fmaf(yA[1][1], yA[1][1],
                                    fmaf(yA[1][2], yA[1][2], yA[1][3] * yA[1][3]))));
        const float s1B0 = wave_sum((yB[0][0] + yB[0][1]) + (yB[0][2] + yB[0][3]));
        const float s2B0 = wave_sum(fmaf(yB[0][0], yB[0][0], fmaf(yB[0][1], yB[0][1],
                                    fmaf(yB[0][2], yB[0][2], yB[0][3] * yB[0][3]))));
        const float s1B1 = wave_sum((yB[1][0] + yB[1][1]) + (yB[1][2] + yB[1][3]));
        const float s2B1 = wave_sum(fmaf(yB[1][0], yB[1][0], fmaf(yB[1][1], yB[1][1],
                                    fmaf(yB[1][2], yB[1][2], yB[1][3] * yB[1][3]))));

        // epilogue: acc += lg*(y*wrs - m*wrs) + w*lb  for each (row, j)
        #pragma unroll
        for (int j = 0; j < 2; ++j) {
            const float s1a = j ? s1A1 : s1A0, s2a = j ? s2A1 : s2A0;
            const float s1b = j ? s1B1 : s1B0, s2b = j ? s2B1 : s2B0;
            const float wa = j ? XA.w : XA.y;
            const float wb = j ? XB.w : XB.y;

            const float mA  = s1a * (1.0f / ODIM);
            const float vA  = s2a * (1.0f / ODIM) - mA * mA;
            const float wrsA = wa * __builtin_amdgcn_rsqf(vA + 1e-5f);
            const float mwA = mA * wrsA;
            const float mB  = s1b * (1.0f / ODIM);
            const float vB  = s2b * (1.0f / ODIM) - mB * mB;
            const float wrsB = wb * __builtin_amdgcn_rsqf(vB + 1e-5f);
            const float mwB = mB * wrsB;

            #define LG(k) (j ? BFHI(UW(Ulg, k)) : BFLO(UW(Ulg, k)))
            #define LB(k) (j ? BFHI(UW(Ulb, k)) : BFLO(UW(Ulb, k)))
            aA0 = fmaf(LG(0), fmaf(yA[j][0], wrsA, -mwA), fmaf(wa, LB(0), aA0));
            aA1 = fmaf(LG(1), fmaf(yA[j][1], wrsA, -mwA), fmaf(wa, LB(1), aA1));
            aA2 = fmaf(LG(2), fmaf(yA[j][2], wrsA, -mwA), fmaf(wa, LB(2), aA2));
            aA3 = fmaf(LG(3), fmaf(yA[j][3], wrsA, -mwA), fmaf(wa, LB(3), aA3));
            aB0 = fmaf(LG(0), fmaf(yB[j][0], wrsB, -mwB), fmaf(wb, LB(0), aB0));
            aB1 = fmaf(LG(1), fmaf(yB[j][1], wrsB, -mwB), fmaf(wb, LB(1), aB1));
            aB2 = fmaf(LG(2), fmaf(yB[j][2], wrsB, -mwB), fmaf(wb, LB(2), aB2));
            aB3 = fmaf(LG(3), fmaf(yB[j][3], wrsB, -mwB), fmaf(wb, LB(3), aB3));
            #undef LG
            #undef LB
        }
        #undef UW
    }

    *(float4*)(out + (size_t)(row0 + rA) * ODIM + o0) = make_float4(aA0, aA1, aA2, aA3);
    *(float4*)(out + (size_t)(row0 + rB) * ODIM + o0) = make_float4(aB0, aB1, aB2, aB3);
}

extern "C" void kernel_launch(void* const* d_in, const int* in_sizes, int n_in,
                              void* d_out, int out_size, void* d_ws, size_t ws_size,
                              hipStream_t stream) {
    const float* x   = (const float*)d_in[0];
    const float* sgw = (const float*)d_in[5];
    const float* sgb = (const float*)d_in[6];
    const float* slg = (const float*)d_in[7];
    const float* slb = (const float*)d_in[8];
    const float* vgw = (const float*)d_in[13];
    const float* vgb = (const float*)d_in[14];
    const float* vsw = (const float*)d_in[15];
    const float* vsb = (const float*)d_in[16];
    const float* vlg = (const float*)d_in[17];
    const float* vlb = (const float*)d_in[18];
    float* out = (float*)d_out;

    const int N = in_sizes[0] / VDIM;      // 4096 rows
    const int grid = N / RPB;              // 256 blocks, 1 per CU

    vsn_fused<<<grid, TPB, 0, stream>>>(x, sgw, sgb, slg, slb,
                                        vgw, vgb, vsw, vsb, vlg, vlb, out);
}